// Round 2
// baseline (417.792 us; speedup 1.0000x reference)
//
#include <hip/hip_runtime.h>
#include <math.h>

// Problem dims (fixed by setup_inputs): B=4, L=4096, D_MODEL=2048, HALF=32
#define M_ROWS 16384   // B*L
#define DM     2048
#define NJ     64      // 2*HALF (interleaved re/im)
#define L_SEQ  4096

typedef __bf16 bf16x8 __attribute__((ext_vector_type(8)));
typedef float  f32x4  __attribute__((ext_vector_type(4)));

// Workspace BYTE offsets. Total ~6.8 MB.
constexpr size_t OB_BBART = 0;                  // bf16 [NJ][DM]   (j-major, k contig)
constexpr size_t OB_CCT   = 262144;             // bf16 [DM][NJ]   (d-major, j contig)
constexpr size_t OB_BU    = 524288;             // f32  [M_ROWS][NJ]
constexpr size_t OB_XSB   = 524288 + 4194304;   // bf16 [M_ROWS][NJ] (packed pairs)

static __device__ __forceinline__ unsigned short f2bf(float f) {
  unsigned int u = __float_as_uint(f);
  u = (u + 0x7fffu + ((u >> 16) & 1u)) >> 16;   // RNE
  return (unsigned short)u;
}

// ---------------------------------------------------------------------------
// Prep: bbarT[j][k] = j-component of B_bar for state n=j>>1 at feature k (bf16),
//       ccT[d][j]   = (j even ? 2*C_re[d][n] : -2*C_im[d][n]) (bf16).
// Per-state constants recomputed per thread (transcendentals are cheap here).
__global__ void k_prep(const float* __restrict__ lam_ur, const float* __restrict__ lam_im,
                       const float* __restrict__ log_dt,
                       const float* __restrict__ Bre, const float* __restrict__ Bim,
                       const float* __restrict__ Cre, const float* __restrict__ Cim,
                       unsigned short* __restrict__ bbarT, unsigned short* __restrict__ ccT) {
  const int idx = blockIdx.x * 256 + threadIdx.x;  // 0..131071
  {  // bbarT: j = idx>>11 (0..63), d = idx&2047 — coalesced read of B_re/B_im and write
    const int j = idx >> 11, d = idx & 2047, n = j >> 1;
    float x = lam_ur[n];
    float sp = (x > 20.f) ? x : log1pf(expf(x));       // softplus
    float lre = -(sp + 1.0e-4f + 0.01f);
    float lim = lam_im[n];
    float dt = expf(log_dt[n]);
    float er = expf(lre * dt);
    float Are = er * cosf(lim * dt);
    float Aim = er * sinf(lim * dt);
    float den = lre * lre + lim * lim;
    float cre = ((Are - 1.f) * lre + Aim * lim) / den;  // (Lam_bar-1)/Lam
    float cim = (Aim * lre - (Are - 1.f) * lim) / den;
    float br = Bre[n * DM + d], bi = Bim[n * DM + d];
    float v = (j & 1) ? (cre * bi + cim * br) : (cre * br - cim * bi);
    bbarT[(size_t)j * DM + d] = f2bf(v);
  }
  {  // ccT: j = idx&63, d = idx>>6 — coalesced write
    const int j = idx & 63, d = idx >> 6, n = j >> 1;
    float v = (j & 1) ? (-2.f * Cim[d * 32 + n]) : (2.f * Cre[d * 32 + n]);
    ccT[(size_t)d * NJ + j] = f2bf(v);
  }
}

// ---------------------------------------------------------------------------
// Bu GEMM, MFMA, LDS-free: bu[row][j] = sum_k u[row][k] * BbarT[j][k].
// Block: 32 rows x 64 cols, K=2048. A-frags straight from global u (fp32->bf16),
// B-frags straight from L2-resident bbarT.
__global__ __launch_bounds__(256) void k_bu(const float* __restrict__ u,
                                            const unsigned short* __restrict__ bbarT,
                                            float* __restrict__ bu) {
  const int t = threadIdx.x;
  const int wave = t >> 6, lane = t & 63;
  const int m0 = blockIdx.x * 32;
  const int rt = wave & 1;             // row-tile (16 rows)
  const int ct0 = (wave >> 1) * 2;     // first of 2 col-tiles
  const int l15 = lane & 15;
  const int kq = (lane >> 4) * 8;      // k sub-offset within a 32-wide k-step
  const float* up = u + (size_t)(m0 + rt * 16 + l15) * DM + kq;
  const bf16x8* b0 = (const bf16x8*)(bbarT + (size_t)(ct0 * 16 + l15) * DM + kq);
  const bf16x8* b1 = (const bf16x8*)(bbarT + (size_t)(ct0 * 16 + 16 + l15) * DM + kq);
  f32x4 acc0 = {0.f, 0.f, 0.f, 0.f}, acc1 = {0.f, 0.f, 0.f, 0.f};
#pragma unroll 4
  for (int k0 = 0; k0 < DM; k0 += 32) {
    float4 v0 = *(const float4*)(up + k0);
    float4 v1 = *(const float4*)(up + k0 + 4);
    bf16x8 a;
    a[0] = (__bf16)v0.x; a[1] = (__bf16)v0.y; a[2] = (__bf16)v0.z; a[3] = (__bf16)v0.w;
    a[4] = (__bf16)v1.x; a[5] = (__bf16)v1.y; a[6] = (__bf16)v1.z; a[7] = (__bf16)v1.w;
    bf16x8 bb0 = b0[k0 >> 3];  // (k0+kq) elements past base, /8 per bf16x8
    bf16x8 bb1 = b1[k0 >> 3];
    acc0 = __builtin_amdgcn_mfma_f32_16x16x32_bf16(a, bb0, acc0, 0, 0, 0);
    acc1 = __builtin_amdgcn_mfma_f32_16x16x32_bf16(a, bb1, acc1, 0, 0, 0);
  }
  // C/D layout: col = lane&15, row = (lane>>4)*4 + i
  const int col0 = ct0 * 16 + l15;
  const int orow = m0 + rt * 16 + (lane >> 4) * 4;
#pragma unroll
  for (int i = 0; i < 4; ++i) {
    bu[(size_t)(orow + i) * NJ + col0] = acc0[i];
    bu[(size_t)(orow + i) * NJ + col0 + 16] = acc1[i];
  }
}

// ---------------------------------------------------------------------------
// Associative scan along L per (b, n): x_t = A*x_{t-1} + Bu_t (complex).
// 16 local steps/thread + Hillis-Steele carry scan (uniform multiplier A^16).
// Output: xsb packed bf16 pairs, row-major [row][NJ] — k_out's A operand.
__global__ __launch_bounds__(256) void k_scan(const float* __restrict__ bu,
                                              const float* __restrict__ lam_ur,
                                              const float* __restrict__ lam_im,
                                              const float* __restrict__ log_dt,
                                              unsigned int* __restrict__ xsb32) {
  __shared__ float2 sbuf[L_SEQ + 256];  // padded: idx' = idx + (idx>>4)
  __shared__ float2 P[256];
  const int n = blockIdx.x;  // 0..31
  const int b = blockIdx.y;  // 0..3
  const int t = threadIdx.x;
  const size_t base = (size_t)b * L_SEQ;
  float x = lam_ur[n];
  float sp = (x > 20.f) ? x : log1pf(expf(x));
  float lre = -(sp + 1.0e-4f + 0.01f);
  float lim = lam_im[n];
  float dt = expf(log_dt[n]);
  float er = expf(lre * dt);
  const float Are = er * cosf(lim * dt);
  const float Aim = er * sinf(lim * dt);
  for (int i = t; i < L_SEQ; i += 256) {
    float2 v = *(const float2*)&bu[(base + i) * NJ + 2 * n];
    sbuf[i + (i >> 4)] = v;
  }
  __syncthreads();
  // Local inclusive scan of 16 consecutive elements.
  float lre16[16], lim16[16];
  float xre = 0.f, xim = 0.f;
#pragma unroll
  for (int i = 0; i < 16; ++i) {
    float2 buv = sbuf[17 * t + i];
    float nr = Are * xre - Aim * xim + buv.x;
    float ni = Are * xim + Aim * xre + buv.y;
    xre = nr; xim = ni;
    lre16[i] = nr; lim16[i] = ni;
  }
  // M = A^16 by repeated squaring.
  float Mre = Are, Mim = Aim;
#pragma unroll
  for (int k = 0; k < 4; ++k) {
    float nr = Mre * Mre - Mim * Mim;
    float ni = 2.f * Mre * Mim;
    Mre = nr; Mim = ni;
  }
  // Hillis-Steele inclusive scan of per-thread carries.
  float pre = xre, pim = xim;
  P[t] = make_float2(pre, pim);
  __syncthreads();
  float msre = Mre, msim = Mim;  // M^s
  for (int s = 1; s < 256; s <<= 1) {
    float2 prev = (t >= s) ? P[t - s] : make_float2(0.f, 0.f);
    __syncthreads();
    pre += msre * prev.x - msim * prev.y;
    pim += msre * prev.y + msim * prev.x;
    P[t] = make_float2(pre, pim);
    float nr = msre * msre - msim * msim;
    float ni = 2.f * msre * msim;
    msre = nr; msim = ni;
    __syncthreads();
  }
  float2 E = (t == 0) ? make_float2(0.f, 0.f) : P[t - 1];
  // x_i_final = local_i + A^{i+1} * E
  float pwre = Are, pwim = Aim;
#pragma unroll
  for (int i = 0; i < 16; ++i) {
    float rre = lre16[i] + pwre * E.x - pwim * E.y;
    float rim = lim16[i] + pwre * E.y + pwim * E.x;
    sbuf[17 * t + i] = make_float2(rre, rim);
    float nr = pwre * Are - pwim * Aim;
    float ni = pwre * Aim + pwim * Are;
    pwre = nr; pwim = ni;
  }
  __syncthreads();
  for (int i = t; i < L_SEQ; i += 256) {
    float2 v = sbuf[i + (i >> 4)];
    xsb32[(base + i) * (NJ / 2) + n] = ((unsigned int)f2bf(v.y) << 16) | f2bf(v.x);
  }
}

// ---------------------------------------------------------------------------
// Output GEMM, MFMA, LDS-free: y[row][d] = sum_j xs[row][j]*ccT[d][j] + D[d]*u[row][d].
// Block: 32 rows x 128 cols. K=64 (2 MFMA k-steps). A-frags from row-major bf16 xs.
__global__ __launch_bounds__(256) void k_out(const unsigned short* __restrict__ xsb,
                                             const unsigned short* __restrict__ ccT,
                                             const float* __restrict__ u,
                                             const float* __restrict__ Dv,
                                             float* __restrict__ y) {
  const int t = threadIdx.x;
  const int wave = t >> 6, lane = t & 63;
  const int m0 = blockIdx.x * 32;
  const int d0 = blockIdx.y * 128;
  const int rt = wave & 1;
  const int ct0 = (wave >> 1) * 4;   // 4 col-tiles of 16
  const int l15 = lane & 15;
  const int kq = (lane >> 4) * 8;
  const int row = m0 + rt * 16 + l15;
  bf16x8 a0 = *(const bf16x8*)(xsb + (size_t)row * NJ + kq);
  bf16x8 a1 = *(const bf16x8*)(xsb + (size_t)row * NJ + 32 + kq);
  f32x4 acc[4] = {{0.f,0.f,0.f,0.f},{0.f,0.f,0.f,0.f},{0.f,0.f,0.f,0.f},{0.f,0.f,0.f,0.f}};
#pragma unroll
  for (int c = 0; c < 4; ++c) {
    const int col = d0 + (ct0 + c) * 16 + l15;
    bf16x8 b0 = *(const bf16x8*)(ccT + (size_t)col * NJ + kq);
    bf16x8 b1 = *(const bf16x8*)(ccT + (size_t)col * NJ + 32 + kq);
    acc[c] = __builtin_amdgcn_mfma_f32_16x16x32_bf16(a0, b0, acc[c], 0, 0, 0);
    acc[c] = __builtin_amdgcn_mfma_f32_16x16x32_bf16(a1, b1, acc[c], 0, 0, 0);
  }
  const int orow = m0 + rt * 16 + (lane >> 4) * 4;
#pragma unroll
  for (int c = 0; c < 4; ++c) {
    const int col = d0 + (ct0 + c) * 16 + l15;
    const float dsc = Dv[col];
#pragma unroll
    for (int i = 0; i < 4; ++i) {
      const size_t off = (size_t)(orow + i) * DM + col;
      y[off] = acc[c][i] + dsc * u[off];
    }
  }
}

// ---------------------------------------------------------------------------
extern "C" void kernel_launch(void* const* d_in, const int* in_sizes, int n_in,
                              void* d_out, int out_size, void* d_ws, size_t ws_size,
                              hipStream_t stream) {
  const float* u      = (const float*)d_in[0];
  const float* lam_ur = (const float*)d_in[1];
  const float* lam_im = (const float*)d_in[2];
  const float* B_re   = (const float*)d_in[3];
  const float* B_im   = (const float*)d_in[4];
  const float* C_re   = (const float*)d_in[5];
  const float* C_im   = (const float*)d_in[6];
  const float* Dv     = (const float*)d_in[7];
  const float* log_dt = (const float*)d_in[8];
  float* y = (float*)d_out;
  char* ws = (char*)d_ws;

  unsigned short* bbarT = (unsigned short*)(ws + OB_BBART);
  unsigned short* ccT   = (unsigned short*)(ws + OB_CCT);
  float*          bu    = (float*)(ws + OB_BU);
  unsigned short* xsb   = (unsigned short*)(ws + OB_XSB);

  k_prep<<<512, 256, 0, stream>>>(lam_ur, lam_im, log_dt, B_re, B_im, C_re, C_im, bbarT, ccT);
  k_bu<<<M_ROWS / 32, 256, 0, stream>>>(u, bbarT, bu);
  k_scan<<<dim3(32, 4), 256, 0, stream>>>(bu, lam_ur, lam_im, log_dt, (unsigned int*)xsb);
  k_out<<<dim3(M_ROWS / 32, DM / 128), 256, 0, stream>>>(xsb, ccT, u, Dv, y);
}

// Round 3
// 301.185 us; speedup vs baseline: 1.3872x; 1.3872x over previous
//
#include <hip/hip_runtime.h>
#include <math.h>

// Problem dims (fixed by setup_inputs): B=4, L=4096, D_MODEL=2048, HALF=32
#define M_ROWS 16384   // B*L
#define DM     2048
#define NJ     64      // 2*HALF (interleaved re/im)
#define L_SEQ  4096

typedef __bf16 bf16x8 __attribute__((ext_vector_type(8)));
typedef float  f32x4  __attribute__((ext_vector_type(4)));

// Workspace BYTE offsets. Total ~6.5 MB.
constexpr size_t OB_BBART = 0;                        // bf16 [NJ][DM]     (j-major, k contig)
constexpr size_t OB_CCT   = 256 * 1024;               // bf16 [DM][NJ]     (d-major, j contig)
constexpr size_t OB_BUT   = 512 * 1024;               // f32  [NJ][M_ROWS] (j-major, row contig)
constexpr size_t OB_XST   = 512 * 1024 + 4194304;     // bf16 [NJ][M_ROWS] (j-major, row contig)

static __device__ __forceinline__ unsigned short f2bf(float f) {
  unsigned int u = __float_as_uint(f);
  u = (u + 0x7fffu + ((u >> 16) & 1u)) >> 16;   // RNE
  return (unsigned short)u;
}

// ---------------------------------------------------------------------------
// Prep: bbarT[j][k] = j-component of B_bar for state n=j>>1 at feature k (bf16),
//       ccT[d][j]   = (j even ? 2*C_re[d][n] : -2*C_im[d][n]) (bf16).
__global__ void k_prep(const float* __restrict__ lam_ur, const float* __restrict__ lam_im,
                       const float* __restrict__ log_dt,
                       const float* __restrict__ Bre, const float* __restrict__ Bim,
                       const float* __restrict__ Cre, const float* __restrict__ Cim,
                       unsigned short* __restrict__ bbarT, unsigned short* __restrict__ ccT) {
  const int idx = blockIdx.x * 256 + threadIdx.x;  // 0..131071
  {  // bbarT: j = idx>>11, d = idx&2047 — coalesced read of B_re/B_im and write
    const int j = idx >> 11, d = idx & 2047, n = j >> 1;
    float x = lam_ur[n];
    float sp = (x > 20.f) ? x : log1pf(expf(x));       // softplus
    float lre = -(sp + 1.0e-4f + 0.01f);
    float lim = lam_im[n];
    float dt = expf(log_dt[n]);
    float er = expf(lre * dt);
    float Are = er * cosf(lim * dt);
    float Aim = er * sinf(lim * dt);
    float den = lre * lre + lim * lim;
    float cre = ((Are - 1.f) * lre + Aim * lim) / den;  // (Lam_bar-1)/Lam
    float cim = (Aim * lre - (Are - 1.f) * lim) / den;
    float br = Bre[n * DM + d], bi = Bim[n * DM + d];
    float v = (j & 1) ? (cre * bi + cim * br) : (cre * br - cim * bi);
    bbarT[(size_t)j * DM + d] = f2bf(v);
  }
  {  // ccT: j = idx&63, d = idx>>6 — coalesced write
    const int j = idx & 63, d = idx >> 6, n = j >> 1;
    float v = (j & 1) ? (-2.f * Cim[d * 32 + n]) : (2.f * Cre[d * 32 + n]);
    ccT[(size_t)d * NJ + j] = f2bf(v);
  }
}

// ---------------------------------------------------------------------------
// Bu GEMM: bu_t[j][row] = sum_k u[row][k] * bbarT[j][k].
// Block = 16 rows x all 64 j; 4 waves, wave w owns j-tile w. u staged via LDS
// (coalesced float4 -> bf16), B-frags straight from L2-resident bbarT.
__global__ __launch_bounds__(256) void k_bu(const float* __restrict__ u,
                                            const unsigned short* __restrict__ bbarT,
                                            float* __restrict__ bu_t) {
  __shared__ __align__(16) unsigned short As[16][72];  // [row][k] bf16, padded
  const int t = threadIdx.x;
  const int wave = t >> 6, lane = t & 63;
  const int m0 = blockIdx.x * 16;
  const int l15 = lane & 15, kq8 = (lane >> 4) * 8;
  const int srow = t >> 4, scol = (t & 15) * 4;        // staging map: 16 rows x 64 k
  const float* up = u + (size_t)(m0 + srow) * DM + scol;
  const unsigned short* bp = bbarT + (size_t)(wave * 16 + l15) * DM + kq8;
  f32x4 acc = {0.f, 0.f, 0.f, 0.f};
  for (int k0 = 0; k0 < DM; k0 += 64) {
    float4 v = *(const float4*)(up + k0);              // coalesced 256B/16-lane rows
    __syncthreads();                                   // prev-iter LDS reads done
    ushort4 w4;
    w4.x = f2bf(v.x); w4.y = f2bf(v.y); w4.z = f2bf(v.z); w4.w = f2bf(v.w);
    *(ushort4*)&As[srow][scol] = w4;
    __syncthreads();
    bf16x8 a0 = *(const bf16x8*)&As[l15][kq8];
    bf16x8 a1 = *(const bf16x8*)&As[l15][32 + kq8];
    bf16x8 b0 = *(const bf16x8*)(bp + k0);
    bf16x8 b1 = *(const bf16x8*)(bp + k0 + 32);
    acc = __builtin_amdgcn_mfma_f32_16x16x32_bf16(a0, b0, acc, 0, 0, 0);
    acc = __builtin_amdgcn_mfma_f32_16x16x32_bf16(a1, b1, acc, 0, 0, 0);
  }
  // C layout: col=lane&15 -> j, rows (lane>>4)*4+i contiguous -> float4 store.
  const int j = wave * 16 + l15;
  const int orow = m0 + (lane >> 4) * 4;
  *(f32x4*)&bu_t[(size_t)j * M_ROWS + orow] = acc;
}

// ---------------------------------------------------------------------------
// Associative scan along L per (b, n): x_t = A*x_{t-1} + Bu_t (complex).
// j-major streams in and out -> fully coalesced global access.
__global__ __launch_bounds__(256) void k_scan(const float* __restrict__ bu_t,
                                              const float* __restrict__ lam_ur,
                                              const float* __restrict__ lam_im,
                                              const float* __restrict__ log_dt,
                                              unsigned short* __restrict__ xs_t) {
  __shared__ float sre[L_SEQ + 256], sim[L_SEQ + 256];  // padded: e' = e + (e>>4)
  __shared__ float2 P[256];
  const int n = blockIdx.x;  // 0..31
  const int b = blockIdx.y;  // 0..3
  const int t = threadIdx.x;
  float x = lam_ur[n];
  float sp = (x > 20.f) ? x : log1pf(expf(x));
  float lre = -(sp + 1.0e-4f + 0.01f);
  float lim = lam_im[n];
  float dt = expf(log_dt[n]);
  float er = expf(lre * dt);
  const float Are = er * cosf(lim * dt);
  const float Aim = er * sinf(lim * dt);
  const float* pr = bu_t + (size_t)(2 * n) * M_ROWS + (size_t)b * L_SEQ;
  const float* pi = bu_t + (size_t)(2 * n + 1) * M_ROWS + (size_t)b * L_SEQ;
#pragma unroll
  for (int i0 = 4 * t; i0 < L_SEQ; i0 += 1024) {
    float4 vr = *(const float4*)(pr + i0);   // coalesced
    float4 vi = *(const float4*)(pi + i0);
    const float rr[4] = {vr.x, vr.y, vr.z, vr.w};
    const float ii[4] = {vi.x, vi.y, vi.z, vi.w};
#pragma unroll
    for (int q = 0; q < 4; ++q) {
      int e = i0 + q, ee = e + (e >> 4);
      sre[ee] = rr[q];
      sim[ee] = ii[q];
    }
  }
  __syncthreads();
  // Local inclusive scan of 16 consecutive elements (LDS base 17*t).
  float lre16[16], lim16[16];
  float xre = 0.f, xim = 0.f;
#pragma unroll
  for (int i = 0; i < 16; ++i) {
    float bre = sre[17 * t + i], bim = sim[17 * t + i];
    float nr = Are * xre - Aim * xim + bre;
    float ni = Are * xim + Aim * xre + bim;
    xre = nr; xim = ni;
    lre16[i] = nr; lim16[i] = ni;
  }
  // M = A^16 by repeated squaring.
  float Mre = Are, Mim = Aim;
#pragma unroll
  for (int k = 0; k < 4; ++k) {
    float nr = Mre * Mre - Mim * Mim;
    float ni = 2.f * Mre * Mim;
    Mre = nr; Mim = ni;
  }
  // Hillis-Steele inclusive scan of per-thread carries.
  float pre = xre, pim = xim;
  P[t] = make_float2(pre, pim);
  __syncthreads();
  float msre = Mre, msim = Mim;  // M^s
  for (int s = 1; s < 256; s <<= 1) {
    float2 prev = (t >= s) ? P[t - s] : make_float2(0.f, 0.f);
    __syncthreads();
    pre += msre * prev.x - msim * prev.y;
    pim += msre * prev.y + msim * prev.x;
    P[t] = make_float2(pre, pim);
    float nr = msre * msre - msim * msim;
    float ni = 2.f * msre * msim;
    msre = nr; msim = ni;
    __syncthreads();
  }
  float2 E = (t == 0) ? make_float2(0.f, 0.f) : P[t - 1];
  // x_i_final = local_i + A^{i+1} * E; write back to LDS for packed store.
  float pwre = Are, pwim = Aim;
#pragma unroll
  for (int i = 0; i < 16; ++i) {
    sre[17 * t + i] = lre16[i] + pwre * E.x - pwim * E.y;
    sim[17 * t + i] = lim16[i] + pwre * E.y + pwim * E.x;
    float nr = pwre * Are - pwim * Aim;
    float ni = pwre * Aim + pwim * Are;
    pwre = nr; pwim = ni;
  }
  __syncthreads();
  // Packed bf16-pair stores, j-major: fully coalesced uint streams.
  unsigned int* xr = (unsigned int*)(xs_t + (size_t)(2 * n) * M_ROWS + (size_t)b * L_SEQ);
  unsigned int* xi = (unsigned int*)(xs_t + (size_t)(2 * n + 1) * M_ROWS + (size_t)b * L_SEQ);
  for (int i = t; i < L_SEQ / 2; i += 256) {
    int e0 = 2 * i, e1 = 2 * i + 1;
    int p0 = e0 + (e0 >> 4), p1 = e1 + (e1 >> 4);
    xr[i] = ((unsigned int)f2bf(sre[p1]) << 16) | f2bf(sre[p0]);
    xi[i] = ((unsigned int)f2bf(sim[p1]) << 16) | f2bf(sim[p0]);
  }
}

// ---------------------------------------------------------------------------
// Output GEMM: y[row][d] = sum_j xs[row][j]*ccT[d][j] + D[d]*u[row][d].
// Block = 64 rows x 128 cols. A-tile via LDS transpose from j-major xs_t;
// epilogue via LDS fp32 transpose -> float4-coalesced u loads and y stores.
__global__ __launch_bounds__(256) void k_out(const unsigned short* __restrict__ xs_t,
                                             const unsigned short* __restrict__ ccT,
                                             const float* __restrict__ u,
                                             const float* __restrict__ Dv,
                                             float* __restrict__ y) {
  __shared__ __align__(16) char smem[64 * 132 * 4];            // 33.8 KB, reused
  unsigned short (*As)[72] = (unsigned short(*)[72])smem;      // [64 rows][72] bf16
  float (*Es)[132] = (float(*)[132])smem;                      // [64 rows][132] f32
  const int t = threadIdx.x;
  const int wave = t >> 6, lane = t & 63;
  const int m0 = blockIdx.x * 64;
  const int d0 = blockIdx.y * 128;
  const int l15 = lane & 15, kq8 = (lane >> 4) * 8;
  // Stage A tile: 64 j x 64 rows (uint = 2 packed rows), coalesced 128B/32-lane.
#pragma unroll
  for (int p = 0; p < 8; ++p) {
    int idx = t + 256 * p;  // 0..2047
    int j = idx >> 5, r2 = idx & 31;
    unsigned int v = *(const unsigned int*)(xs_t + (size_t)j * M_ROWS + m0 + 2 * r2);
    As[2 * r2][j] = (unsigned short)(v & 0xffffu);
    As[2 * r2 + 1][j] = (unsigned short)(v >> 16);
  }
  __syncthreads();
  bf16x8 a0 = *(const bf16x8*)&As[wave * 16 + l15][kq8];
  bf16x8 a1 = *(const bf16x8*)&As[wave * 16 + l15][32 + kq8];
  f32x4 acc[8];
#pragma unroll
  for (int c = 0; c < 8; ++c) acc[c] = (f32x4){0.f, 0.f, 0.f, 0.f};
#pragma unroll
  for (int c = 0; c < 8; ++c) {
    const unsigned short* cp = ccT + (size_t)(d0 + c * 16 + l15) * NJ + kq8;
    bf16x8 b0 = *(const bf16x8*)cp;
    bf16x8 b1 = *(const bf16x8*)(cp + 32);
    acc[c] = __builtin_amdgcn_mfma_f32_16x16x32_bf16(a0, b0, acc[c], 0, 0, 0);
    acc[c] = __builtin_amdgcn_mfma_f32_16x16x32_bf16(a1, b1, acc[c], 0, 0, 0);
  }
  __syncthreads();  // done with As; smem becomes Es
#pragma unroll
  for (int c = 0; c < 8; ++c)
#pragma unroll
    for (int i = 0; i < 4; ++i)
      Es[wave * 16 + (lane >> 4) * 4 + i][c * 16 + l15] = acc[c][i];
  __syncthreads();
  // Coalesced epilogue: float4 per lane, 512B per 32 consecutive lanes.
#pragma unroll
  for (int p = 0; p < 8; ++p) {
    int idx = t + 256 * p;       // 0..2047
    int row = idx >> 5;          // 0..63
    int c4 = (idx & 31) * 4;     // 0..124
    f32x4 e = *(const f32x4*)&Es[row][c4];
    const size_t off = (size_t)(m0 + row) * DM + d0 + c4;
    float4 uu = *(const float4*)&u[off];
    float4 dd = *(const float4*)&Dv[d0 + c4];
    float4 o;
    o.x = e[0] + dd.x * uu.x;
    o.y = e[1] + dd.y * uu.y;
    o.z = e[2] + dd.z * uu.z;
    o.w = e[3] + dd.w * uu.w;
    *(float4*)&y[off] = o;
  }
}

// ---------------------------------------------------------------------------
extern "C" void kernel_launch(void* const* d_in, const int* in_sizes, int n_in,
                              void* d_out, int out_size, void* d_ws, size_t ws_size,
                              hipStream_t stream) {
  const float* u      = (const float*)d_in[0];
  const float* lam_ur = (const float*)d_in[1];
  const float* lam_im = (const float*)d_in[2];
  const float* B_re   = (const float*)d_in[3];
  const float* B_im   = (const float*)d_in[4];
  const float* C_re   = (const float*)d_in[5];
  const float* C_im   = (const float*)d_in[6];
  const float* Dv     = (const float*)d_in[7];
  const float* log_dt = (const float*)d_in[8];
  float* y = (float*)d_out;
  char* ws = (char*)d_ws;

  unsigned short* bbarT = (unsigned short*)(ws + OB_BBART);
  unsigned short* ccT   = (unsigned short*)(ws + OB_CCT);
  float*          bu_t  = (float*)(ws + OB_BUT);
  unsigned short* xs_t  = (unsigned short*)(ws + OB_XST);

  k_prep<<<512, 256, 0, stream>>>(lam_ur, lam_im, log_dt, B_re, B_im, C_re, C_im, bbarT, ccT);
  k_bu<<<M_ROWS / 16, 256, 0, stream>>>(u, bbarT, bu_t);
  k_scan<<<dim3(32, 4), 256, 0, stream>>>(bu_t, lam_ur, lam_im, log_dt, xs_t);
  k_out<<<dim3(M_ROWS / 64, DM / 128), 256, 0, stream>>>(xs_t, ccT, u, Dv, y);
}